// Round 10
// baseline (1702.959 us; speedup 1.0000x reference)
//
#include <hip/hip_runtime.h>

#define SEQ 512
#define BATCH 64
#define NN 1024
#define SS 64
#define NT 512            // threads per block; block h covers neurons h*512..h*512+511

typedef unsigned long long u64;

#define ALOAD64(p)    __hip_atomic_load((p), __ATOMIC_RELAXED, __HIP_MEMORY_SCOPE_AGENT)
#define ASTORE64(p,v) __hip_atomic_store((p), (v), __ATOMIC_RELAXED, __HIP_MEMORY_SCOPE_AGENT)

// ---- transpose W1 (1024x1024 f32): W1T[i*N+j] = W1[j*N+i] ----
__global__ void transpose1(const float* __restrict__ A, float* __restrict__ At) {
    __shared__ float tile[32][33];
    int bx = blockIdx.x * 32, by = blockIdx.y * 32;
    int tx = threadIdx.x, ty = threadIdx.y;   // block 32x8
#pragma unroll
    for (int r = 0; r < 32; r += 8)
        tile[ty + r][tx] = A[(by + ty + r) * NN + (bx + tx)];
    __syncthreads();
#pragma unroll
    for (int r = 0; r < 32; r += 8)
        At[(bx + ty + r) * NN + (by + tx)] = tile[tx][ty + r];
}

// 16-lane inclusive prefix scan via DPP row_shr (pure VALU).
__device__ __forceinline__ int dpp_scan16(int x) {
    x += __builtin_amdgcn_update_dpp(0, x, 0x111, 0xF, 0xF, false); // row_shr:1
    x += __builtin_amdgcn_update_dpp(0, x, 0x112, 0xF, 0xF, false); // row_shr:2
    x += __builtin_amdgcn_update_dpp(0, x, 0x114, 0xF, 0xF, false); // row_shr:4
    x += __builtin_amdgcn_update_dpp(0, x, 0x118, 0xF, 0xF, false); // row_shr:8
    return x;
}

// ---- main LIF kernel: 2 blocks per batch (halves of the neuron dim).
// LAGGED-FLUSH protocol: step t publishes its counts (A exact, B speculative);
// step t+1 consumes them (flush of t) -> the cross-block exchange has a full
// step of slack and never stalls. Outputs of step s are written at its flush.
// Word: [s+1:16][pB:24][pA:24], p = cnt | cnt2<<12, parity slots, memset-0 tags.
// Rare path (layer-1 spikes): spiking waves publish ballot bitmaps + RELEASE
// word; both halves rebuild I2 from bitmaps, re-exchange corrected B counts.
__global__ __launch_bounds__(NT, 2) void lif_kernel(
    const float* __restrict__ W1T, const float* __restrict__ W2,
    const float* __restrict__ decay1, const float* __restrict__ decay2,
    const float* __restrict__ th1, const float* __restrict__ th2,
    const float* __restrict__ init1, const float* __restrict__ init2,
    const int* __restrict__ inp_ids, const int* __restrict__ inp_num,
    u64* __restrict__ cwt, u64* __restrict__ cwt2, u64* __restrict__ cbal,
    float* __restrict__ out)
{
    const int bid  = blockIdx.x;
    const int h    = bid >> 6;            // half: 0 or 1
    const int b    = bid & 63;            // batch element
    const int i    = threadIdx.x;         // 0..511
    const int lane = i & 63;
    const int wid  = i >> 6;              // 0..7
    const int n    = (h << 9) + i;        // my neuron
    const int G    = (h << 3) + wid;      // global group 0..15

    u64* wtb  = cwt  + (size_t)b * 32;    // [parity][16] count words
    u64* wtb2 = cwt2 + (size_t)b * 32;    // [parity][16] corrected-B (rare)
    u64* balg = cbal + (size_t)b * 32;    // [parity][16] spike bitmaps (rare)

    float v1     = init1[b * NN + n];
    float v2post = init2[b * NN + n];     // post-reset state after flushed step
    float v2p    = 0.0f;                  // pre-reset spec value of step t (set at E)
    const float d1 = decay1[n], d2 = decay2[n];
    const float t1 = th1[n],    t2 = th2[n];
    const float t1b = __fmul_rn(0.9f, t1);
    const float t2b = __fmul_rn(0.9f, t2);
    const float omd1 = __fadd_rn(1.0f, -d1);
    const float omd2 = __fadd_rn(1.0f, -d2);

    // output layout (floats): ids1 | ids2 | cnt1 | cnt2 | st1 | st2
    float* out_ids1 = out;
    float* out_ids2 = out + (size_t)SEQ * BATCH * SS;
    float* out_cnt1 = out + (size_t)2 * SEQ * BATCH * SS;
    float* out_cnt2 = out_cnt1 + (size_t)SEQ * BATCH * 2;
    float* out_st1  = out_cnt2 + (size_t)SEQ * BATCH * 2;
    float* out_st2  = out_st1  + (size_t)SEQ * BATCH * NN;

    const unsigned long long lmask_lt = (1ull << lane) - 1ull;

    u64 bal1_prev = 0;                    // layer-1 spike ballot of flushed step

    // flush(s): consume word(s) (published a full step ago), verify speculation,
    // write ALL outputs of step s, set v2post = true post-reset state after s.
    auto FLUSH = [&](int s) {
        const int par = s & 1;
        u64 w;
        for (;;) {
            w = ALOAD64(&wtb[par * 16 + (lane & 15)]);
            if (__all((int)(unsigned)(w >> 48) == (s + 1))) break;
            __builtin_amdgcn_s_sleep(1);
        }
        const int pAv = (int)(w & 0xFFFFFF);
        const int pBv = (int)((w >> 24) & 0xFFFFFF);

        const int xA = dpp_scan16(pAv);
        const int totA_pack = __builtin_amdgcn_readlane(xA, 15);
        const int offA = G ? __builtin_amdgcn_readlane(xA, G - 1) : 0;
        const int totalA  = totA_pack & 0xFFF;
        const int total2A = (totA_pack >> 12) & 0xFFF;
        const bool spk1p  = (bal1_prev >> lane) & 1ull;
        const int lt1   = (offA & 0xFFF) + (int)__popcll(bal1_prev & lmask_lt);
        const int slot1 = spk1p ? lt1 : (totalA + n - lt1);

        int totalB, total2B, lt2;
        bool spk2p;
        if (totalA > 0) {
            // RARE corrective path: rebuild I2 from published spike bitmaps.
            __builtin_amdgcn_fence(__ATOMIC_ACQUIRE, "agent");
            float I2 = 0.0f;
            for (int g = 0; g < 16; ++g) {                 // ascending neuron order
                const int cg = __builtin_amdgcn_readlane(pAv, g) & 0xFFF;
                if (cg) {
                    const u64 bm = ALOAD64(&balg[par * 16 + g]);
                    for (u64 m = bm; m; m &= (m - 1)) {
                        const int sid = (g << 6) + (int)__builtin_ctzll(m);
                        I2 = __fadd_rn(I2, W2[(size_t)n * NN + sid]); // W2T[sid][n]
                    }
                }
            }
            v2p = __fadd_rn(v2p, __fmul_rn(omd2, I2));     // correct spec (spec had I2=0)
            spk2p = v2p > t2;
            const u64 cb1 = __ballot(spk2p);
            const u64 cb2 = __ballot(v2p > t2b);
            if (lane == 0) {
                const u64 q = (u64)((unsigned)__popcll(cb1) | ((unsigned)__popcll(cb2) << 12));
                ASTORE64(&wtb2[par * 16 + G], ((u64)(s + 1) << 48) | q);
            }
            u64 w2;
            for (;;) {
                w2 = ALOAD64(&wtb2[par * 16 + (lane & 15)]);
                if (__all((int)(unsigned)(w2 >> 48) == (s + 1))) break;
                __builtin_amdgcn_s_sleep(1);
            }
            const int xB = dpp_scan16((int)(w2 & 0xFFFFFF));
            const int totB_pack = __builtin_amdgcn_readlane(xB, 15);
            const int offB = G ? __builtin_amdgcn_readlane(xB, G - 1) : 0;
            totalB  = totB_pack & 0xFFF;
            total2B = (totB_pack >> 12) & 0xFFF;
            lt2 = (offB & 0xFFF) + (int)__popcll(cb1 & lmask_lt);
        } else {
            // common path: speculation exact; scan partner's spec-B counts.
            spk2p = v2p > t2;
            const u64 sb1 = __ballot(spk2p);
            const int xB = dpp_scan16(pBv);
            const int totB_pack = __builtin_amdgcn_readlane(xB, 15);
            const int offB = G ? __builtin_amdgcn_readlane(xB, G - 1) : 0;
            totalB  = totB_pack & 0xFFF;
            total2B = (totB_pack >> 12) & 0xFFF;
            lt2 = (offB & 0xFFF) + (int)__popcll(sb1 & lmask_lt);
        }
        const int slot2 = spk2p ? lt2 : (totalB + n - lt2);
        const float v2out = spk2p ? 0.0f : v2p;
        v2post = v2out;

        // ---- outputs of step s ----
        const size_t row = (size_t)s * BATCH + b;
        if (slot1 < SS)
            __builtin_nontemporal_store((float)n, &out_ids1[row * SS + slot1]);
        if (slot2 < SS)
            __builtin_nontemporal_store((float)n, &out_ids2[row * SS + slot2]);
        if (h == 0 && i == 0) {
            __builtin_nontemporal_store((float)totalA,  &out_cnt1[row * 2 + 0]);
            __builtin_nontemporal_store((float)total2A, &out_cnt1[row * 2 + 1]);
            __builtin_nontemporal_store((float)totalB,  &out_cnt2[row * 2 + 0]);
            __builtin_nontemporal_store((float)total2B, &out_cnt2[row * 2 + 1]);
        }
        __builtin_nontemporal_store(v2out, &out_st2[row * NN + n]);
    };

    // ---- prologue: gather(0) via scalar ids, 8-granular ----
    int num_cur = inp_num[b];
    float a[64];
    {
        const int* ids0 = inp_ids + (size_t)b * SS;      // uniform -> s_load path
        const int nch = (num_cur + 7) >> 3;
#pragma unroll
        for (int c = 0; c < 8; ++c)
            if (c < nch)
#pragma unroll
                for (int j = 0; j < 8; ++j)
                    a[c * 8 + j] = W1T[((size_t)ids0[c * 8 + j] << 10) + n];
    }

    for (int t = 0; t < SEQ; ++t) {
        // ---- A: accumulate I1(t) from resident a[] (8-granular masking) ----
        float I1;
        {
            float s0 = 0.0f, s1 = 0.0f, s2 = 0.0f, s3 = 0.0f;
#pragma unroll
            for (int c = 0; c < 8; ++c) {
                const int lim = num_cur - (c << 3);
                if (lim >= 8) {
#pragma unroll
                    for (int j = 0; j < 8; j += 4) {
                        s0 = __fadd_rn(s0, a[c * 8 + j + 0]);
                        s1 = __fadd_rn(s1, a[c * 8 + j + 1]);
                        s2 = __fadd_rn(s2, a[c * 8 + j + 2]);
                        s3 = __fadd_rn(s3, a[c * 8 + j + 3]);
                    }
                } else if (lim > 0) {
#pragma unroll
                    for (int j = 0; j < 8; j += 4) {
                        s0 = __fadd_rn(s0, (j + 0 < lim) ? a[c * 8 + j + 0] : 0.0f);
                        s1 = __fadd_rn(s1, (j + 1 < lim) ? a[c * 8 + j + 1] : 0.0f);
                        s2 = __fadd_rn(s2, (j + 2 < lim) ? a[c * 8 + j + 2] : 0.0f);
                        s3 = __fadd_rn(s3, (j + 3 < lim) ? a[c * 8 + j + 3] : 0.0f);
                    }
                }
            }
            I1 = __fadd_rn(__fadd_rn(s0, s1), __fadd_rn(s2, s3));
        }

        // ---- B: layer-1 update (exact, purely local) ----
        v1 = __fadd_rn(__fmul_rn(d1, v1), __fmul_rn(omd1, I1));
        const bool spk1 = v1 > t1;
        const u64 bal1 = __ballot(spk1);
        const u64 baln = __ballot(v1 > t1b);      // near-count on pre-reset v1
        if (spk1) v1 = 0.0f;

        // ---- C: flush step t-1 (word has a full step of slack -> no stall) ----
        if (t > 0) FLUSH(t - 1);

        // ---- D: issue gather(t+1); pinned here by the fence below ----
        {
            const int tn = (t + 1 < SEQ) ? t + 1 : 0;    // wrap: tail loads harmless
            const int num_next = inp_num[tn * BATCH + b];
            const int* idsn = inp_ids + ((size_t)tn * BATCH + b) * SS;
            const int nch = (num_next + 7) >> 3;
#pragma unroll
            for (int c = 0; c < 8; ++c)
                if (c < nch)
#pragma unroll
                    for (int j = 0; j < 8; ++j)
                        a[c * 8 + j] = W1T[((size_t)idsn[c * 8 + j] << 10) + n];
            num_cur = num_next;
        }
        asm volatile("" ::: "memory");   // forbid sinking the gather loads below

        // ---- E: speculative layer-2 pre-reset value + publish word(t) ----
        v2p = __fmul_rn(d2, v2post);                  // exact when totalA(t)==0
        const u64 sb1 = __ballot(v2p > t2);
        const u64 sb2 = __ballot(v2p > t2b);
        if (lane == 0) {
            const u64 pA = (u64)((unsigned)__popcll(bal1) | ((unsigned)__popcll(baln) << 12));
            const u64 pB = (u64)((unsigned)__popcll(sb1)  | ((unsigned)__popcll(sb2)  << 12));
            const u64 word = ((u64)(t + 1) << 48) | (pB << 24) | pA;
            if (bal1) {   // rare: bitmap first, then RELEASE word (orders both)
                ASTORE64(&balg[(t & 1) * 16 + G], bal1);
                __hip_atomic_store(&wtb[(t & 1) * 16 + G], word,
                                   __ATOMIC_RELEASE, __HIP_MEMORY_SCOPE_AGENT);
            } else {
                ASTORE64(&wtb[(t & 1) * 16 + G], word);
            }
        }

        // ---- F: st1(t) (v1 exact, post-reset) ----
        __builtin_nontemporal_store(v1, &out_st1[((size_t)t * BATCH + b) * NN + n]);

        // ---- G: rotate ----
        bal1_prev = bal1;
    }

    // ---- epilogue: flush the last step ----
    FLUSH(SEQ - 1);
}

extern "C" void kernel_launch(void* const* d_in, const int* in_sizes, int n_in,
                              void* d_out, int out_size, void* d_ws, size_t ws_size,
                              hipStream_t stream) {
    const float* W1     = (const float*)d_in[0];
    const float* W2     = (const float*)d_in[1];
    const float* decay1 = (const float*)d_in[2];
    const float* decay2 = (const float*)d_in[3];
    const float* th1    = (const float*)d_in[4];
    const float* th2    = (const float*)d_in[5];
    const float* init1  = (const float*)d_in[6];
    const float* init2  = (const float*)d_in[7];
    const int* inp_ids  = (const int*)d_in[8];
    const int* inp_num  = (const int*)d_in[9];
    float* out = (float*)d_out;

    float* W1T = (float*)d_ws;                          // 4 MB
    char*  comm = (char*)d_ws + (size_t)NN * NN * 4;
    u64* cwt  = (u64*)(comm);                           // 64*2*16*8 = 16 KB
    u64* cwt2 = (u64*)(comm + 16384);                   // 16 KB
    u64* cbal = (u64*)(comm + 32768);                   // 16 KB
    // zero tags/bitmaps each launch (stale generations from prior dispatch)
    hipMemsetAsync(comm, 0, 49152, stream);

    dim3 tb(32, 8, 1), tg(NN / 32, NN / 32, 1);
    transpose1<<<tg, tb, 0, stream>>>(W1, W1T);
    lif_kernel<<<2 * BATCH, NT, 0, stream>>>(W1T, W2, decay1, decay2, th1, th2,
                                             init1, init2, inp_ids, inp_num,
                                             cwt, cwt2, cbal, out);
}

// Round 12
// 944.965 us; speedup vs baseline: 1.8021x; 1.8021x over previous
//
#include <hip/hip_runtime.h>

#define SEQ 512
#define BATCH 64
#define NN 1024
#define SS 64

typedef float v4f __attribute__((ext_vector_type(4)));   // native vec: NT-store OK

// lgkm-only barrier (no vmcnt drain): LDS settled, global loads/stores in flight.
#define RAW_BARRIER() asm volatile("s_waitcnt lgkmcnt(0)\n\ts_barrier" ::: "memory")

// ---- transpose W1 (1024x1024 f32): W1T[i*N+j] = W1[j*N+i] ----
__global__ void transpose1(const float* __restrict__ A, float* __restrict__ At) {
    __shared__ float tile[32][33];
    int bx = blockIdx.x * 32, by = blockIdx.y * 32;
    int tx = threadIdx.x, ty = threadIdx.y;   // block 32x8
#pragma unroll
    for (int r = 0; r < 32; r += 8)
        tile[ty + r][tx] = A[(by + ty + r) * NN + (bx + tx)];
    __syncthreads();
#pragma unroll
    for (int r = 0; r < 32; r += 8)
        At[(bx + ty + r) * NN + (by + tx)] = tile[tx][ty + r];
}

// ---- phase 1: I1[tt,b,n] = sum_{s<num} W1T[ids[s], n]  (no serial dependency;
// one block per (tt,b), thread j owns n=4j..4j+3, 16B loads, 256 CUs busy).
// FP order matches R9: stripe accumulator by row%4, final (s0+s1)+(s2+s3).
__global__ __launch_bounds__(256) void gather_kernel(
    const float* __restrict__ W1T,
    const int* __restrict__ inp_ids, const int* __restrict__ inp_num,
    float* __restrict__ I1buf, int t0)
{
    const int bid = blockIdx.x;
    const int tt  = bid >> 6;
    const int b   = bid & 63;
    const int t   = t0 + tt;
    const int j4  = threadIdx.x << 2;              // n base
    const int num = inp_num[t * BATCH + b];
    const int* ids = inp_ids + ((size_t)t * BATCH + b) * SS;  // uniform -> s_load

    v4f a0 = {0,0,0,0}, a1 = a0, a2 = a0, a3 = a0;
    const int num4 = num & ~3;
    for (int r = 0; r < num4; r += 4) {
        const v4f w0 = *(const v4f*)(W1T + ((size_t)ids[r+0] << 10) + j4);
        const v4f w1 = *(const v4f*)(W1T + ((size_t)ids[r+1] << 10) + j4);
        const v4f w2 = *(const v4f*)(W1T + ((size_t)ids[r+2] << 10) + j4);
        const v4f w3 = *(const v4f*)(W1T + ((size_t)ids[r+3] << 10) + j4);
#pragma unroll
        for (int k = 0; k < 4; ++k) {
            a0[k] = __fadd_rn(a0[k], w0[k]);
            a1[k] = __fadd_rn(a1[k], w1[k]);
            a2[k] = __fadd_rn(a2[k], w2[k]);
            a3[k] = __fadd_rn(a3[k], w3[k]);
        }
    }
    const int rem = num & 3;
    if (rem > 0) {
        const v4f w0 = *(const v4f*)(W1T + ((size_t)ids[num4+0] << 10) + j4);
#pragma unroll
        for (int k = 0; k < 4; ++k) a0[k] = __fadd_rn(a0[k], w0[k]);
        if (rem > 1) {
            const v4f w1 = *(const v4f*)(W1T + ((size_t)ids[num4+1] << 10) + j4);
#pragma unroll
            for (int k = 0; k < 4; ++k) a1[k] = __fadd_rn(a1[k], w1[k]);
        }
        if (rem > 2) {
            const v4f w2 = *(const v4f*)(W1T + ((size_t)ids[num4+2] << 10) + j4);
#pragma unroll
            for (int k = 0; k < 4; ++k) a2[k] = __fadd_rn(a2[k], w2[k]);
        }
    }
    v4f o;
#pragma unroll
    for (int k = 0; k < 4; ++k)
        o[k] = __fadd_rn(__fadd_rn(a0[k], a1[k]), __fadd_rn(a2[k], a3[k]));
    __builtin_nontemporal_store(o,
        (v4f*)(I1buf + ((size_t)tt * BATCH + b) * NN + j4));
}

// ---- phase 2: serial LIF recurrence with precomputed I1. One block per batch,
// 256 threads (4 waves), 4 neurons/thread, 1 lgkm-barrier/step, no gather.
__global__ __launch_bounds__(256, 1) void lif_kernel(
    const float* __restrict__ I1buf, const float* __restrict__ W2,
    const float* __restrict__ decay1, const float* __restrict__ decay2,
    const float* __restrict__ th1, const float* __restrict__ th2,
    const float* __restrict__ init1, const float* __restrict__ init2,
    float* __restrict__ state, float* __restrict__ out,
    int t0, int nsteps)
{
    const int b    = blockIdx.x;
    const int i    = threadIdx.x;      // 0..255
    const int lane = i & 63;
    const int w    = i >> 6;           // wave 0..3
    const int n0   = i << 2;           // neurons n0..n0+3

    __shared__ int lds_c1[2][4];       // [step parity][wave] packed cnt|cnt2<<16
    __shared__ int lds_c2[2][4];
    __shared__ int lds_slots[NN];      // rare path only

    float v1[4], v2[4], d1v[4], d2v[4], o1v[4], o2v[4];
    float t1v[4], t2v[4], t1bv[4], t2bv[4];
    const float* v1src = t0 ? (state + 0 * BATCH * NN) : init1;
    const float* v2src = t0 ? (state + 1 * BATCH * NN) : init2;
#pragma unroll
    for (int k = 0; k < 4; ++k) {
        const int n = n0 + k;
        v1[k] = v1src[b * NN + n];  v2[k] = v2src[b * NN + n];
        d1v[k] = decay1[n];  d2v[k] = decay2[n];
        t1v[k] = th1[n];     t2v[k] = th2[n];
        t1bv[k] = __fmul_rn(0.9f, t1v[k]);
        t2bv[k] = __fmul_rn(0.9f, t2v[k]);
        o1v[k] = __fadd_rn(1.0f, -d1v[k]);
        o2v[k] = __fadd_rn(1.0f, -d2v[k]);
    }

    float* out_ids1 = out;
    float* out_ids2 = out + (size_t)SEQ * BATCH * SS;
    float* out_cnt1 = out + (size_t)2 * SEQ * BATCH * SS;
    float* out_cnt2 = out_cnt1 + (size_t)SEQ * BATCH * 2;
    float* out_st1  = out_cnt2 + (size_t)SEQ * BATCH * 2;
    float* out_st2  = out_st1  + (size_t)SEQ * BATCH * NN;

    // depth-2 prefetch of I1 (affine addresses, no dependency)
    v4f f0 = *(const v4f*)(I1buf + ((size_t)0 * BATCH + b) * NN + n0);
    v4f f1 = (nsteps > 1)
        ? *(const v4f*)(I1buf + ((size_t)1 * BATCH + b) * NN + n0) : f0;

    for (int tt = 0; tt < nsteps; ++tt) {
        const int t   = t0 + tt;
        const int par = tt & 1;
        const v4f f = f0;
        f0 = f1;
        if (tt + 2 < nsteps)
            f1 = *(const v4f*)(I1buf + ((size_t)(tt + 2) * BATCH + b) * NN + n0);

        // ---- layer 1 update ----
        int c1 = 0, cn1 = 0, m1 = 0;
#pragma unroll
        for (int k = 0; k < 4; ++k) {
            v1[k] = __fadd_rn(__fmul_rn(d1v[k], v1[k]), __fmul_rn(o1v[k], f[k]));
            const bool s = v1[k] > t1v[k];
            c1 += s; m1 |= (int)s << k;
            cn1 += (v1[k] > t1bv[k]);
        }
        // ---- layer 2 speculative (I2=0; exact when no layer-1 spikes) ----
        int c2 = 0, cn2 = 0, m2 = 0;
        float v2p[4];
#pragma unroll
        for (int k = 0; k < 4; ++k) {
            v2p[k] = __fmul_rn(d2v[k], v2[k]);
            const bool s = v2p[k] > t2v[k];
            c2 += s; m2 |= (int)s << k;
            cn2 += (v2p[k] > t2bv[k]);
        }

        // ---- 64-lane inclusive scans (packed cnt | cnt2<<16), LDS exchange ----
        int S1 = c1 | (cn1 << 16);
        int S2 = c2 | (cn2 << 16);
#pragma unroll
        for (int d = 1; d < 64; d <<= 1) {
            const int y1 = __shfl_up(S1, d);
            const int y2 = __shfl_up(S2, d);
            if (lane >= d) { S1 += y1; S2 += y2; }
        }
        if (lane == 63) { lds_c1[par][w] = S1; lds_c2[par][w] = S2; }
        RAW_BARRIER();                                   // the step's one barrier
        int tot1 = 0, off1 = 0, tot2 = 0, off2 = 0;
#pragma unroll
        for (int ww = 0; ww < 4; ++ww) {
            const int x1 = lds_c1[par][ww];
            const int x2 = lds_c2[par][ww];
            tot1 += x1; tot2 += x2;
            if (ww < w) { off1 += x1; off2 += x2; }
        }
        const int totalA  = tot1 & 0xFFFF;
        const int total2A = tot1 >> 16;
        const int exclA   = (off1 & 0xFFFF) + (S1 & 0xFFFF) - c1;

        const size_t row = (size_t)t * BATCH + b;

        // ---- ids1 scatter + v1 reset + st1 ----
        {
            int run = 0;
            v4f sv;
#pragma unroll
            for (int k = 0; k < 4; ++k) {
                const bool s = (m1 >> k) & 1;
                const int lt = exclA + run;
                run += s;
                const int slot = s ? lt : (totalA + (n0 + k) - lt);
                if (slot < SS)
                    __builtin_nontemporal_store((float)(n0 + k),
                                                &out_ids1[row * SS + slot]);
                sv[k] = s ? 0.0f : v1[k];
                v1[k] = sv[k];
            }
            __builtin_nontemporal_store(sv, (v4f*)(out_st1 + row * NN + n0));
        }
        if (i == 0) {
            __builtin_nontemporal_store((float)totalA,  &out_cnt1[row * 2 + 0]);
            __builtin_nontemporal_store((float)total2A, &out_cnt1[row * 2 + 1]);
        }

        // ---- layer 2 resolve: rare corrective path (block-uniform) ----
        if (totalA > 0) {
            int run = 0;
#pragma unroll
            for (int k = 0; k < 4; ++k)
                if ((m1 >> k) & 1) { lds_slots[exclA + run] = n0 + k; ++run; }
            RAW_BARRIER();
            float I2[4] = {0.0f, 0.0f, 0.0f, 0.0f};
            for (int kk = 0; kk < totalA; ++kk) {
                const int sid = lds_slots[kk];           // ascending neuron order
#pragma unroll
                for (int k = 0; k < 4; ++k)              // W2T[sid][n] == W2[n][sid]
                    I2[k] = __fadd_rn(I2[k], W2[(size_t)(n0 + k) * NN + sid]);
            }
            c2 = 0; cn2 = 0; m2 = 0;
#pragma unroll
            for (int k = 0; k < 4; ++k) {
                v2p[k] = __fadd_rn(__fmul_rn(d2v[k], v2[k]), __fmul_rn(o2v[k], I2[k]));
                const bool s = v2p[k] > t2v[k];
                c2 += s; m2 |= (int)s << k;
                cn2 += (v2p[k] > t2bv[k]);
            }
            S2 = c2 | (cn2 << 16);
#pragma unroll
            for (int d = 1; d < 64; d <<= 1) {
                const int y = __shfl_up(S2, d);
                if (lane >= d) S2 += y;
            }
            if (lane == 63) lds_c2[par][w] = S2;         // overwrite spec (all read)
            RAW_BARRIER();
            tot2 = 0; off2 = 0;
#pragma unroll
            for (int ww = 0; ww < 4; ++ww) {
                const int x2 = lds_c2[par][ww];
                tot2 += x2;
                if (ww < w) off2 += x2;
            }
        }
        const int totalB  = tot2 & 0xFFFF;
        const int total2B = tot2 >> 16;
        const int exclB   = (off2 & 0xFFFF) + (S2 & 0xFFFF) - c2;

        // ---- ids2 scatter + v2 reset + st2 ----
        {
            int run = 0;
            v4f sv;
#pragma unroll
            for (int k = 0; k < 4; ++k) {
                const bool s = (m2 >> k) & 1;
                const int lt = exclB + run;
                run += s;
                const int slot = s ? lt : (totalB + (n0 + k) - lt);
                if (slot < SS)
                    __builtin_nontemporal_store((float)(n0 + k),
                                                &out_ids2[row * SS + slot]);
                sv[k] = s ? 0.0f : v2p[k];
                v2[k] = sv[k];
            }
            __builtin_nontemporal_store(sv, (v4f*)(out_st2 + row * NN + n0));
        }
        if (i == 0) {
            __builtin_nontemporal_store((float)totalB,  &out_cnt2[row * 2 + 0]);
            __builtin_nontemporal_store((float)total2B, &out_cnt2[row * 2 + 1]);
        }
    }

    // ---- persist state for the next chunk ----
#pragma unroll
    for (int k = 0; k < 4; ++k) {
        state[0 * BATCH * NN + b * NN + n0 + k] = v1[k];
        state[1 * BATCH * NN + b * NN + n0 + k] = v2[k];
    }
}

extern "C" void kernel_launch(void* const* d_in, const int* in_sizes, int n_in,
                              void* d_out, int out_size, void* d_ws, size_t ws_size,
                              hipStream_t stream) {
    const float* W1     = (const float*)d_in[0];
    const float* W2     = (const float*)d_in[1];
    const float* decay1 = (const float*)d_in[2];
    const float* decay2 = (const float*)d_in[3];
    const float* th1    = (const float*)d_in[4];
    const float* th2    = (const float*)d_in[5];
    const float* init1  = (const float*)d_in[6];
    const float* init2  = (const float*)d_in[7];
    const int* inp_ids  = (const int*)d_in[8];
    const int* inp_num  = (const int*)d_in[9];
    float* out = (float*)d_out;

    float* W1T   = (float*)d_ws;                                // 4 MB
    float* state = (float*)((char*)d_ws + (size_t)NN * NN * 4); // 512 KB
    float* I1buf = state + (size_t)2 * BATCH * NN;
    const size_t used  = (size_t)NN * NN * 4 + (size_t)2 * BATCH * NN * 4;
    const size_t avail = ws_size > used ? ws_size - used : 0;
    int tc = (int)(avail / ((size_t)BATCH * NN * 4));           // steps per chunk
    if (tc > SEQ) tc = SEQ;
    if (tc < 1) tc = 1;

    dim3 tb(32, 8, 1), tg(NN / 32, NN / 32, 1);
    transpose1<<<tg, tb, 0, stream>>>(W1, W1T);
    for (int t0 = 0; t0 < SEQ; t0 += tc) {
        const int nst = (SEQ - t0 < tc) ? (SEQ - t0) : tc;
        gather_kernel<<<nst * BATCH, 256, 0, stream>>>(W1T, inp_ids, inp_num,
                                                       I1buf, t0);
        lif_kernel<<<BATCH, 256, 0, stream>>>(I1buf, W2, decay1, decay2, th1, th2,
                                              init1, init2, state, out, t0, nst);
    }
}

// Round 13
// 905.053 us; speedup vs baseline: 1.8816x; 1.0441x over previous
//
#include <hip/hip_runtime.h>

#define SEQ 512
#define BATCH 64
#define NN 1024
#define SS 64

typedef float v4f __attribute__((ext_vector_type(4)));
typedef unsigned long long u64;

// lgkm-only barrier (no vmcnt drain): LDS settled, global loads/stores in flight.
#define RAW_BARRIER() asm volatile("s_waitcnt lgkmcnt(0)\n\ts_barrier" ::: "memory")

// ---- transpose W1 (1024x1024 f32): W1T[i*N+j] = W1[j*N+i] ----
__global__ void transpose1(const float* __restrict__ A, float* __restrict__ At) {
    __shared__ float tile[32][33];
    int bx = blockIdx.x * 32, by = blockIdx.y * 32;
    int tx = threadIdx.x, ty = threadIdx.y;   // block 32x8
#pragma unroll
    for (int r = 0; r < 32; r += 8)
        tile[ty + r][tx] = A[(by + ty + r) * NN + (bx + tx)];
    __syncthreads();
#pragma unroll
    for (int r = 0; r < 32; r += 8)
        At[(bx + ty + r) * NN + (by + tx)] = tile[tx][ty + r];
}

// ---- phase 1: I1[tt,b,n] = sum_{s<num} W1T[ids[s], n].  One block per (t,b),
// thread j owns n=4j..4j+3. ids preloaded wholesale (one scalar-wait), chunks
// fully unrolled with block-uniform guards. FP order identical to round 12:
// row r -> accumulator a[r%4]; final (a0+a1)+(a2+a3). Cached store (L2/L3
// resident for the consumer).
__global__ __launch_bounds__(256) void gather_kernel(
    const float* __restrict__ W1T,
    const int* __restrict__ inp_ids, const int* __restrict__ inp_num,
    float* __restrict__ I1buf, int t0)
{
    const int bid = blockIdx.x;
    const int tt  = bid >> 6;
    const int b   = bid & 63;
    const int t   = t0 + tt;
    const int j4  = threadIdx.x << 2;              // n base
    const int num = inp_num[t * BATCH + b];
    const int* ids = inp_ids + ((size_t)t * BATCH + b) * SS;  // uniform -> s_load

    v4f a0 = {0,0,0,0}, a1 = a0, a2 = a0, a3 = a0;
    const int nch = num >> 2;                      // full chunks of 4
    const int rem = num & 3;
#pragma unroll
    for (int c = 0; c < 16; ++c) {
        if (c < nch) {                             // block-uniform
            const int r = c << 2;
            const v4f w0 = *(const v4f*)(W1T + ((size_t)ids[r+0] << 10) + j4);
            const v4f w1 = *(const v4f*)(W1T + ((size_t)ids[r+1] << 10) + j4);
            const v4f w2 = *(const v4f*)(W1T + ((size_t)ids[r+2] << 10) + j4);
            const v4f w3 = *(const v4f*)(W1T + ((size_t)ids[r+3] << 10) + j4);
#pragma unroll
            for (int k = 0; k < 4; ++k) {
                a0[k] = __fadd_rn(a0[k], w0[k]);
                a1[k] = __fadd_rn(a1[k], w1[k]);
                a2[k] = __fadd_rn(a2[k], w2[k]);
                a3[k] = __fadd_rn(a3[k], w3[k]);
            }
        }
    }
    if (rem > 0) {
        const int r4 = nch << 2;
        const v4f w0 = *(const v4f*)(W1T + ((size_t)ids[r4+0] << 10) + j4);
#pragma unroll
        for (int k = 0; k < 4; ++k) a0[k] = __fadd_rn(a0[k], w0[k]);
        if (rem > 1) {
            const v4f w1 = *(const v4f*)(W1T + ((size_t)ids[r4+1] << 10) + j4);
#pragma unroll
            for (int k = 0; k < 4; ++k) a1[k] = __fadd_rn(a1[k], w1[k]);
        }
        if (rem > 2) {
            const v4f w2 = *(const v4f*)(W1T + ((size_t)ids[r4+2] << 10) + j4);
#pragma unroll
            for (int k = 0; k < 4; ++k) a2[k] = __fadd_rn(a2[k], w2[k]);
        }
    }
    v4f o;
#pragma unroll
    for (int k = 0; k < 4; ++k)
        o[k] = __fadd_rn(__fadd_rn(a0[k], a1[k]), __fadd_rn(a2[k], a3[k]));
    *(v4f*)(I1buf + ((size_t)tt * BATCH + b) * NN + j4) = o;   // cached store
}

// ---- phase 2: serial LIF recurrence, deferred-output pipeline.
// One block per batch, 256 threads (4 waves), 4 neurons/thread.
// State updates are lane-local; cross-wave data (totals/offsets) is published
// at step t (one u64/wave: c1|cn1<<16|c2<<32|cn2<<48) and consumed at t+1
// AFTER the intervening barrier -> the LDS round-trip never waits.
// No shfl scans: lane prefixes come from ballots + popc(lmask).
__global__ __launch_bounds__(256, 1) void lif_kernel(
    const float* __restrict__ I1buf, const float* __restrict__ W2,
    const float* __restrict__ decay1, const float* __restrict__ decay2,
    const float* __restrict__ th1, const float* __restrict__ th2,
    const float* __restrict__ init1, const float* __restrict__ init2,
    float* __restrict__ state, float* __restrict__ out,
    int t0, int nsteps)
{
    const int b    = blockIdx.x;
    const int i    = threadIdx.x;      // 0..255
    const int lane = i & 63;
    const int w    = i >> 6;           // wave 0..3
    const int n0   = i << 2;           // neurons n0..n0+3

    __shared__ u64 lds_w[2][4];        // [parity][wave] packed counts
    __shared__ u64 lds_wc[2][4];       // corrected layer-2 counts (rare)
    __shared__ int lds_slots[NN];      // rare path only

    float v1[4], v2[4], d1v[4], d2v[4], o1v[4], o2v[4];
    float t1v[4], t2v[4], t1bv[4], t2bv[4];
    const float* v1src = t0 ? (state + 0 * BATCH * NN) : init1;
    const float* v2src = t0 ? (state + 1 * BATCH * NN) : init2;
#pragma unroll
    for (int k = 0; k < 4; ++k) {
        const int n = n0 + k;
        v1[k] = v1src[b * NN + n];  v2[k] = v2src[b * NN + n];
        d1v[k] = decay1[n];  d2v[k] = decay2[n];
        t1v[k] = th1[n];     t2v[k] = th2[n];
        t1bv[k] = __fmul_rn(0.9f, t1v[k]);
        t2bv[k] = __fmul_rn(0.9f, t2v[k]);
        o1v[k] = __fadd_rn(1.0f, -d1v[k]);
        o2v[k] = __fadd_rn(1.0f, -d2v[k]);
    }

    float* out_ids1 = out;
    float* out_ids2 = out + (size_t)SEQ * BATCH * SS;
    float* out_cnt1 = out + (size_t)2 * SEQ * BATCH * SS;
    float* out_cnt2 = out_cnt1 + (size_t)SEQ * BATCH * 2;
    float* out_st1  = out_cnt2 + (size_t)SEQ * BATCH * 2;
    float* out_st2  = out_st1  + (size_t)SEQ * BATCH * NN;

    const u64 lmask_lt = (1ull << lane) - 1ull;

    // pending (step t's lane-local results, resolved & output at t+1)
    u64 B1p[4], B2p[4];                // spike ballots (layer1 exact, layer2 spec)
    float v2pp[4];                     // spec pre-reset v2 of pending step

    // consume(s, ppar): output everything for step s; resolve v2 state.
    // Uses: lds_w[ppar] (barrier-synced), B1p/B2p/v2pp/v1 (pending regs).
    auto CONSUME = [&](int s, int ppar) {
        const u64* wp = lds_w[ppar];
        const u64 x0 = wp[0], x1 = wp[1], x2 = wp[2], x3 = wp[3];
        const u64 tot = x0 + x1 + x2 + x3;           // fields <=1024, no carry
        const u64 off = (w > 0 ? x0 : 0) + (w > 1 ? x1 : 0) + (w > 2 ? x2 : 0);
        const int totalA  = (int)(tot & 0xFFFF);
        const int total2A = (int)((tot >> 16) & 0xFFFF);
        const int woff1   = (int)(off & 0xFFFF);

        // layer-1 lane prefix from ballots (ascending neuron order)
        const int T1 = (int)(__popcll(B1p[0] & lmask_lt) + __popcll(B1p[1] & lmask_lt)
                           + __popcll(B1p[2] & lmask_lt) + __popcll(B1p[3] & lmask_lt));
        const size_t row = (size_t)s * BATCH + b;

        int run = 0;
        int lt1s[4]; bool bk1[4];
#pragma unroll
        for (int k = 0; k < 4; ++k) {
            bk1[k] = (B1p[k] >> lane) & 1ull;
            lt1s[k] = woff1 + T1 + run;
            run += bk1[k];
            const int slot = bk1[k] ? lt1s[k] : (totalA + (n0 + k) - lt1s[k]);
            if (slot < SS)
                __builtin_nontemporal_store((float)(n0 + k),
                                            &out_ids1[row * SS + slot]);
        }
        {   // st1: v1 currently holds post-reset state of step s
            const v4f sv = {v1[0], v1[1], v1[2], v1[3]};
            __builtin_nontemporal_store(sv, (v4f*)(out_st1 + row * NN + n0));
        }
        if (i == 0) {
            __builtin_nontemporal_store((float)totalA,  &out_cnt1[row * 2 + 0]);
            __builtin_nontemporal_store((float)total2A, &out_cnt1[row * 2 + 1]);
        }

        // layer-2 resolve
        int totalB, total2B, woff2;
        u64 B2u[4]; float v2u[4];
        if (totalA > 0) {
            // RARE corrective path (block-uniform)
            run = 0;
#pragma unroll
            for (int k = 0; k < 4; ++k)
                if (bk1[k]) lds_slots[lt1s[k]] = n0 + k;
            RAW_BARRIER();
            float I2[4] = {0.0f, 0.0f, 0.0f, 0.0f};
            for (int kk = 0; kk < totalA; ++kk) {
                const int sid = lds_slots[kk];           // ascending neuron order
#pragma unroll
                for (int k = 0; k < 4; ++k)              // W2T[sid][n] == W2[n][sid]
                    I2[k] = __fadd_rn(I2[k], W2[(size_t)(n0 + k) * NN + sid]);
            }
            u64 Bn2c[4];
#pragma unroll
            for (int k = 0; k < 4; ++k) {
                v2u[k] = __fadd_rn(v2pp[k], __fmul_rn(o2v[k], I2[k]));
                B2u[k] = __ballot(v2u[k] > t2v[k]);
                Bn2c[k] = __ballot(v2u[k] > t2bv[k]);
            }
            const u64 c2c  = __popcll(B2u[0]) + __popcll(B2u[1])
                           + __popcll(B2u[2]) + __popcll(B2u[3]);
            const u64 cn2c = __popcll(Bn2c[0]) + __popcll(Bn2c[1])
                           + __popcll(Bn2c[2]) + __popcll(Bn2c[3]);
            if (lane == 0) lds_wc[ppar][w] = c2c | (cn2c << 16);
            RAW_BARRIER();
            const u64* cp = lds_wc[ppar];
            const u64 y0 = cp[0], y1 = cp[1], y2 = cp[2], y3 = cp[3];
            const u64 ct = y0 + y1 + y2 + y3;
            const u64 co = (w > 0 ? y0 : 0) + (w > 1 ? y1 : 0) + (w > 2 ? y2 : 0);
            totalB  = (int)(ct & 0xFFFF);
            total2B = (int)((ct >> 16) & 0xFFFF);
            woff2   = (int)(co & 0xFFFF);
        } else {
#pragma unroll
            for (int k = 0; k < 4; ++k) { B2u[k] = B2p[k]; v2u[k] = v2pp[k]; }
            totalB  = (int)((tot >> 32) & 0xFFFF);
            total2B = (int)(tot >> 48);
            woff2   = (int)((off >> 32) & 0xFFFF);
        }

        const int T2 = (int)(__popcll(B2u[0] & lmask_lt) + __popcll(B2u[1] & lmask_lt)
                           + __popcll(B2u[2] & lmask_lt) + __popcll(B2u[3] & lmask_lt));
        run = 0;
        v4f sv2;
#pragma unroll
        for (int k = 0; k < 4; ++k) {
            const bool bk = (B2u[k] >> lane) & 1ull;
            const int lt = woff2 + T2 + run;
            run += bk;
            const int slot = bk ? lt : (totalB + (n0 + k) - lt);
            if (slot < SS)
                __builtin_nontemporal_store((float)(n0 + k),
                                            &out_ids2[row * SS + slot]);
            sv2[k] = bk ? 0.0f : v2u[k];
            v2[k] = sv2[k];                             // resolved state
        }
        __builtin_nontemporal_store(sv2, (v4f*)(out_st2 + row * NN + n0));
        if (i == 0) {
            __builtin_nontemporal_store((float)totalB,  &out_cnt2[row * 2 + 0]);
            __builtin_nontemporal_store((float)total2B, &out_cnt2[row * 2 + 1]);
        }
    };

    // I1 prefetch ring, depth 2
    v4f f0 = *(const v4f*)(I1buf + ((size_t)0 * BATCH + b) * NN + n0);
    v4f f1 = (nsteps > 1)
        ? *(const v4f*)(I1buf + ((size_t)1 * BATCH + b) * NN + n0) : f0;

    for (int tt = 0; tt < nsteps; ++tt) {
        const int par = tt & 1;
        // issue I1(tt+2) early (independent; covered by whole iteration)
        v4f f2 = f0;
        if (tt + 2 < nsteps)
            f2 = *(const v4f*)(I1buf + ((size_t)(tt + 2) * BATCH + b) * NN + n0);

        // ---- consume step tt-1 (LDS data barrier-synced a full step ago) ----
        if (tt > 0) CONSUME(t0 + tt - 1, par ^ 1);

        // ---- compute step tt (lane-local) ----
        const v4f f = f0; f0 = f1; f1 = f2;
        u64 Bn1[4], Bn2[4];
#pragma unroll
        for (int k = 0; k < 4; ++k) {
            v1[k] = __fadd_rn(__fmul_rn(d1v[k], v1[k]), __fmul_rn(o1v[k], f[k]));
            B1p[k] = __ballot(v1[k] > t1v[k]);
            Bn1[k] = __ballot(v1[k] > t1bv[k]);
            if ((B1p[k] >> lane) & 1ull) v1[k] = 0.0f;   // reset (post-reset kept)
            v2pp[k] = __fmul_rn(d2v[k], v2[k]);          // spec (exact if no L1 spikes)
            B2p[k] = __ballot(v2pp[k] > t2v[k]);
            Bn2[k] = __ballot(v2pp[k] > t2bv[k]);
        }
        const u64 c1  = __popcll(B1p[0]) + __popcll(B1p[1])
                      + __popcll(B1p[2]) + __popcll(B1p[3]);
        const u64 cn1 = __popcll(Bn1[0]) + __popcll(Bn1[1])
                      + __popcll(Bn1[2]) + __popcll(Bn1[3]);
        const u64 c2  = __popcll(B2p[0]) + __popcll(B2p[1])
                      + __popcll(B2p[2]) + __popcll(B2p[3]);
        const u64 cn2 = __popcll(Bn2[0]) + __popcll(Bn2[1])
                      + __popcll(Bn2[2]) + __popcll(Bn2[3]);
        if (lane == 0)
            lds_w[par][w] = c1 | (cn1 << 16) | (c2 << 32) | (cn2 << 48);

        RAW_BARRIER();                 // syncs lds_w[par] for next iteration
    }

    // ---- epilogue: consume the last step ----
    CONSUME(t0 + nsteps - 1, (nsteps - 1) & 1);

    // persist state for the next chunk
#pragma unroll
    for (int k = 0; k < 4; ++k) {
        state[0 * BATCH * NN + b * NN + n0 + k] = v1[k];
        state[1 * BATCH * NN + b * NN + n0 + k] = v2[k];
    }
}

extern "C" void kernel_launch(void* const* d_in, const int* in_sizes, int n_in,
                              void* d_out, int out_size, void* d_ws, size_t ws_size,
                              hipStream_t stream) {
    const float* W1     = (const float*)d_in[0];
    const float* W2     = (const float*)d_in[1];
    const float* decay1 = (const float*)d_in[2];
    const float* decay2 = (const float*)d_in[3];
    const float* th1    = (const float*)d_in[4];
    const float* th2    = (const float*)d_in[5];
    const float* init1  = (const float*)d_in[6];
    const float* init2  = (const float*)d_in[7];
    const int* inp_ids  = (const int*)d_in[8];
    const int* inp_num  = (const int*)d_in[9];
    float* out = (float*)d_out;

    float* W1T   = (float*)d_ws;                                // 4 MB
    float* state = (float*)((char*)d_ws + (size_t)NN * NN * 4); // 512 KB
    float* I1buf = state + (size_t)2 * BATCH * NN;
    const size_t used  = (size_t)NN * NN * 4 + (size_t)2 * BATCH * NN * 4;
    const size_t avail = ws_size > used ? ws_size - used : 0;
    int tc = (int)(avail / ((size_t)BATCH * NN * 4));           // steps per chunk
    if (tc > SEQ) tc = SEQ;
    if (tc < 1) tc = 1;

    dim3 tb(32, 8, 1), tg(NN / 32, NN / 32, 1);
    transpose1<<<tg, tb, 0, stream>>>(W1, W1T);
    for (int t0 = 0; t0 < SEQ; t0 += tc) {
        const int nst = (SEQ - t0 < tc) ? (SEQ - t0) : tc;
        gather_kernel<<<nst * BATCH, 256, 0, stream>>>(W1T, inp_ids, inp_num,
                                                       I1buf, t0);
        lif_kernel<<<BATCH, 256, 0, stream>>>(I1buf, W2, decay1, decay2, th1, th2,
                                              init1, init2, state, out, t0, nst);
    }
}